// Round 1
// baseline (952.064 us; speedup 1.0000x reference)
//
#include <hip/hip_runtime.h>
#include <cstdint>
#include <cstddef>

typedef __attribute__((ext_vector_type(8))) short bf16x8;
typedef __attribute__((ext_vector_type(8))) unsigned short ushort8_t;
typedef __attribute__((ext_vector_type(4))) float f32x4;

__device__ __forceinline__ unsigned short f2bf(float f) {
    union { float f; uint32_t u; } c; c.f = f;
    uint32_t u = c.u + 0x7fffu + ((c.u >> 16) & 1u);
    return (unsigned short)(u >> 16);
}
__device__ __forceinline__ float bf2f(unsigned short h) {
    union { uint32_t u; float f; } c; c.u = ((uint32_t)h) << 16;
    return c.f;
}

// ---------------------------------------------------------------------------
// GEMM: C[M=4096 x N] = A[4096 x 2048] * B[2048 x N]
// A: fp32 or bf16(ushort), B: fp32, C: bf16(ushort) or fp32.
// 64x64 block tile, BK=32, 4 waves; wave w owns rows w*16, all 64 cols.
// ---------------------------------------------------------------------------
template <typename AT, typename CT>
__global__ __launch_bounds__(256) void gemm_k(const AT* __restrict__ A,
                                              const float* __restrict__ B,
                                              CT* __restrict__ C, int N) {
    __shared__ unsigned short As[64][40];   // [m][k], pad to 40 (80B rows, 16B aligned)
    __shared__ unsigned short Bs[64][40];   // [n][k] (transposed), pad 40

    const int t = threadIdx.x;
    const int m0 = blockIdx.y << 6, n0 = blockIdx.x << 6;
    const int w = t >> 6, lane = t & 63, l15 = lane & 15, quad = lane >> 4;
    const int ar = t >> 2, ac = (t & 3) << 3;   // A stage: row 0..63, col8 0/8/16/24
    const int bk = t >> 3, bn = (t & 7) << 3;   // B stage: k 0..31, n8 0..56

    f32x4 acc[4] = {};

    for (int k0 = 0; k0 < 2048; k0 += 32) {
        // stage A -> As (convert to bf16 if needed)
        if constexpr (sizeof(AT) == 4) {
            const float* ap = (const float*)A + (size_t)(m0 + ar) * 2048 + k0 + ac;
            float4 f0 = *(const float4*)ap;
            float4 f1 = *(const float4*)(ap + 4);
            ushort8_t vv;
            vv[0] = f2bf(f0.x); vv[1] = f2bf(f0.y); vv[2] = f2bf(f0.z); vv[3] = f2bf(f0.w);
            vv[4] = f2bf(f1.x); vv[5] = f2bf(f1.y); vv[6] = f2bf(f1.z); vv[7] = f2bf(f1.w);
            *(ushort8_t*)&As[ar][ac] = vv;
        } else {
            const unsigned short* ap = (const unsigned short*)A + (size_t)(m0 + ar) * 2048 + k0 + ac;
            *(ushort8_t*)&As[ar][ac] = *(const ushort8_t*)ap;
        }
        // stage B -> Bs transposed [n][k]
        {
            const float* bp = B + (size_t)(k0 + bk) * N + n0 + bn;
            float4 g0 = *(const float4*)bp;
            float4 g1 = *(const float4*)(bp + 4);
            Bs[bn + 0][bk] = f2bf(g0.x); Bs[bn + 1][bk] = f2bf(g0.y);
            Bs[bn + 2][bk] = f2bf(g0.z); Bs[bn + 3][bk] = f2bf(g0.w);
            Bs[bn + 4][bk] = f2bf(g1.x); Bs[bn + 5][bk] = f2bf(g1.y);
            Bs[bn + 6][bk] = f2bf(g1.z); Bs[bn + 7][bk] = f2bf(g1.w);
        }
        __syncthreads();

        bf16x8 a = *(bf16x8*)&As[(w << 4) + l15][quad << 3];
#pragma unroll
        for (int nt = 0; nt < 4; ++nt) {
            bf16x8 bf = *(bf16x8*)&Bs[(nt << 4) + l15][quad << 3];
            acc[nt] = __builtin_amdgcn_mfma_f32_16x16x32_bf16(a, bf, acc[nt], 0, 0, 0);
        }
        __syncthreads();
    }

#pragma unroll
    for (int nt = 0; nt < 4; ++nt)
#pragma unroll
        for (int r = 0; r < 4; ++r) {
            int row = m0 + (w << 4) + (quad << 2) + r;
            int col = n0 + (nt << 4) + l15;
            float vv = acc[nt][r];
            if constexpr (sizeof(CT) == 2)
                ((unsigned short*)C)[(size_t)row * N + col] = f2bf(vv);
            else
                ((float*)C)[(size_t)row * N + col] = vv;
        }
}

// ---------------------------------------------------------------------------
// RoPE in place. One thread owns one (row, head) 64-dim vector -> no race.
// Matches reference: out[d] = x[d]*cos(t*f[d/2]) + rh[d]*sin(t*f[d/2]),
// rh[d] = d<32 ? -x[2d+1] : x[2(d-32)],  f[i] = 10000^(-i/32).
// ---------------------------------------------------------------------------
__global__ __launch_bounds__(256) void rope_k(unsigned short* __restrict__ buf, int hshift) {
    const int idx = blockIdx.x * 256 + threadIdx.x;
    const int row = idx >> hshift;
    const int tt = row & 2047;
    unsigned short* p = buf + (size_t)idx * 64;

    float x[64];
#pragma unroll
    for (int i = 0; i < 8; ++i) {
        ushort8_t v = *(const ushort8_t*)(p + i * 8);
#pragma unroll
        for (int j = 0; j < 8; ++j) x[i * 8 + j] = bf2f(v[j]);
    }
    float cs[32], sn[32];
    const float ft = (float)tt;
#pragma unroll
    for (int i = 0; i < 32; ++i) {
        // inv_freq = 10000^(-i/32) = 2^(-i*log2(10000)/32)
        float invf = exp2f(-0.4152410118609253f * (float)i);
        float ang = ft * invf;
        sn[i] = sinf(ang);
        cs[i] = cosf(ang);
    }
#pragma unroll
    for (int i = 0; i < 8; ++i) {
        ushort8_t v;
#pragma unroll
        for (int j = 0; j < 8; ++j) {
            int d = i * 8 + j;
            float rh = (d < 32) ? -x[2 * d + 1] : x[2 * (d - 32)];
            float y = x[d] * cs[d >> 1] + rh * sn[d >> 1];
            v[j] = f2bf(y);
        }
        *(ushort8_t*)(p + i * 8) = v;
    }
}

// ---------------------------------------------------------------------------
// Flash attention. Block = (qb, h, b): one head, 64 query rows.
// 4 waves; wave w owns q rows w*16..w*16+15.
// ---------------------------------------------------------------------------
__global__ __launch_bounds__(256) void attn_k(const unsigned short* __restrict__ q,
                                              const unsigned short* __restrict__ k,
                                              const unsigned short* __restrict__ v,
                                              unsigned short* __restrict__ att) {
    __shared__ unsigned short Qs[64][72];  // [q][d]
    __shared__ unsigned short Ks[64][72];  // [key][d]
    __shared__ unsigned short Vs[64][72];  // [d][key] (transposed)
    __shared__ unsigned short Ps[64][72];  // [q][key]

    const int t = threadIdx.x;
    const int qb = blockIdx.x, h = blockIdx.y, b = blockIdx.z;
    const int kvh = h >> 2;
    const int w = t >> 6, lane = t & 63, l15 = lane & 15, quad = lane >> 4;
    const int sr = t >> 2, sd = (t & 3) << 4;
    const size_t rowbase = (size_t)b * 2048;

    {
        const unsigned short* qp = q + (rowbase + qb * 64 + sr) * 2048 + h * 64 + sd;
        *(ushort8_t*)&Qs[sr][sd]     = *(const ushort8_t*)qp;
        *(ushort8_t*)&Qs[sr][sd + 8] = *(const ushort8_t*)(qp + 8);
    }
    __syncthreads();
    bf16x8 aq0 = *(bf16x8*)&Qs[(w << 4) + l15][quad << 3];
    bf16x8 aq1 = *(bf16x8*)&Qs[(w << 4) + l15][32 + (quad << 3)];

    f32x4 acc_o[4] = {};
    float m_i[4] = {-INFINITY, -INFINITY, -INFINITY, -INFINITY};
    float l_i[4] = {0.f, 0.f, 0.f, 0.f};

    for (int kb = 0; kb <= qb; ++kb) {
        {
            const unsigned short* kp = k + (rowbase + kb * 64 + sr) * 512 + kvh * 64 + sd;
            *(ushort8_t*)&Ks[sr][sd]     = *(const ushort8_t*)kp;
            *(ushort8_t*)&Ks[sr][sd + 8] = *(const ushort8_t*)(kp + 8);
            const unsigned short* vp = v + (rowbase + kb * 64 + sr) * 512 + kvh * 64 + sd;
            ushort8_t v0 = *(const ushort8_t*)vp;
            ushort8_t v1 = *(const ushort8_t*)(vp + 8);
#pragma unroll
            for (int j = 0; j < 8; ++j) {
                Vs[sd + j][sr]     = v0[j];
                Vs[sd + 8 + j][sr] = v1[j];
            }
        }
        __syncthreads();

        // S = Q K^T  (wave's 16 q rows x 64 keys)
        f32x4 s_acc[4] = {};
#pragma unroll
        for (int nt = 0; nt < 4; ++nt) {
            bf16x8 bk0 = *(bf16x8*)&Ks[(nt << 4) + l15][quad << 3];
            bf16x8 bk1 = *(bf16x8*)&Ks[(nt << 4) + l15][32 + (quad << 3)];
            s_acc[nt] = __builtin_amdgcn_mfma_f32_16x16x32_bf16(aq0, bk0, s_acc[nt], 0, 0, 0);
            s_acc[nt] = __builtin_amdgcn_mfma_f32_16x16x32_bf16(aq1, bk1, s_acc[nt], 0, 0, 0);
        }

        // online softmax. lane holds rows quad*4+r, cols nt*16+l15.
        const int qr0 = qb * 64 + (w << 4) + (quad << 2);
        const int kc0 = kb * 64 + l15;
        float pv[4][4];
#pragma unroll
        for (int nt = 0; nt < 4; ++nt)
#pragma unroll
            for (int r = 0; r < 4; ++r) {
                float sv = s_acc[nt][r] * 0.125f;
                pv[nt][r] = (kc0 + (nt << 4) <= qr0 + r) ? sv : -INFINITY;
            }
        float alpha[4];
#pragma unroll
        for (int r = 0; r < 4; ++r) {
            float mx = fmaxf(fmaxf(pv[0][r], pv[1][r]), fmaxf(pv[2][r], pv[3][r]));
#pragma unroll
            for (int off = 1; off < 16; off <<= 1) mx = fmaxf(mx, __shfl_xor(mx, off, 16));
            float mnew = fmaxf(m_i[r], mx);
            float s4 = 0.f;
#pragma unroll
            for (int nt = 0; nt < 4; ++nt) {
                pv[nt][r] = __expf(pv[nt][r] - mnew);
                s4 += pv[nt][r];
            }
#pragma unroll
            for (int off = 1; off < 16; off <<= 1) s4 += __shfl_xor(s4, off, 16);
            float a = __expf(m_i[r] - mnew);
            l_i[r] = l_i[r] * a + s4;
            m_i[r] = mnew;
            alpha[r] = a;
        }
        // P: C-layout -> LDS (round-trip to A-layout)
#pragma unroll
        for (int nt = 0; nt < 4; ++nt)
#pragma unroll
            for (int r = 0; r < 4; ++r)
                Ps[(w << 4) + (quad << 2) + r][(nt << 4) + l15] = f2bf(pv[nt][r]);
        __syncthreads();

#pragma unroll
        for (int dt = 0; dt < 4; ++dt)
#pragma unroll
            for (int r = 0; r < 4; ++r) acc_o[dt][r] *= alpha[r];

        bf16x8 ap0 = *(bf16x8*)&Ps[(w << 4) + l15][quad << 3];
        bf16x8 ap1 = *(bf16x8*)&Ps[(w << 4) + l15][32 + (quad << 3)];
#pragma unroll
        for (int dt = 0; dt < 4; ++dt) {
            bf16x8 bv0 = *(bf16x8*)&Vs[(dt << 4) + l15][quad << 3];
            bf16x8 bv1 = *(bf16x8*)&Vs[(dt << 4) + l15][32 + (quad << 3)];
            acc_o[dt] = __builtin_amdgcn_mfma_f32_16x16x32_bf16(ap0, bv0, acc_o[dt], 0, 0, 0);
            acc_o[dt] = __builtin_amdgcn_mfma_f32_16x16x32_bf16(ap1, bv1, acc_o[dt], 0, 0, 0);
        }
        __syncthreads();
    }

#pragma unroll
    for (int dt = 0; dt < 4; ++dt)
#pragma unroll
        for (int r = 0; r < 4; ++r) {
            float ov = acc_o[dt][r] / l_i[r];
            size_t row = rowbase + qb * 64 + (w << 4) + (quad << 2) + r;
            att[row * 2048 + h * 64 + (dt << 4) + l15] = f2bf(ov);
        }
}

// ---------------------------------------------------------------------------
extern "C" void kernel_launch(void* const* d_in, const int* in_sizes, int n_in,
                              void* d_out, int out_size, void* d_ws, size_t ws_size,
                              hipStream_t stream) {
    const float* x  = (const float*)d_in[0];
    // d_in[1] = mask (causal; structure is known, not read)
    const float* Wq = (const float*)d_in[2];
    const float* Wk = (const float*)d_in[3];
    const float* Wv = (const float*)d_in[4];
    const float* Wo = (const float*)d_in[5];
    float* out = (float*)d_out;

    unsigned short* q    = (unsigned short*)d_ws;            // 4096 x 2048 bf16
    unsigned short* kbuf = q + (size_t)4096 * 2048;          // 4096 x 512
    unsigned short* vbuf = kbuf + (size_t)4096 * 512;        // 4096 x 512
    unsigned short* att  = vbuf + (size_t)4096 * 512;        // 4096 x 2048

    // projections (M=4096, K=2048)
    gemm_k<float, unsigned short><<<dim3(32, 64), 256, 0, stream>>>(x, Wq, q, 2048);
    gemm_k<float, unsigned short><<<dim3(8, 64), 256, 0, stream>>>(x, Wk, kbuf, 512);
    gemm_k<float, unsigned short><<<dim3(8, 64), 256, 0, stream>>>(x, Wv, vbuf, 512);
    // rope q (32 heads -> shift 5), k (8 heads -> shift 3)
    rope_k<<<dim3(512), 256, 0, stream>>>(q, 5);
    rope_k<<<dim3(128), 256, 0, stream>>>(kbuf, 3);
    // attention
    attn_k<<<dim3(32, 32, 2), 256, 0, stream>>>(q, kbuf, vbuf, att);
    // output projection
    gemm_k<unsigned short, float><<<dim3(32, 64), 256, 0, stream>>>(att, Wo, out, 2048);
}

// Round 2
// 538.308 us; speedup vs baseline: 1.7686x; 1.7686x over previous
//
#include <hip/hip_runtime.h>
#include <cstdint>
#include <cstddef>

typedef unsigned short u16;
typedef __attribute__((ext_vector_type(8))) short bf16x8;
typedef __attribute__((ext_vector_type(8))) unsigned short u16x8;
typedef __attribute__((ext_vector_type(4))) unsigned short u16x4;
typedef __attribute__((ext_vector_type(4))) float f32x4;

__device__ __forceinline__ unsigned short f2bf(float f) {
    union { float f; uint32_t u; } c; c.f = f;
    uint32_t u = c.u + 0x7fffu + ((c.u >> 16) & 1u);
    return (unsigned short)(u >> 16);
}
__device__ __forceinline__ float bf2f(unsigned short h) {
    union { uint32_t u; float f; } c; c.u = ((uint32_t)h) << 16;
    return c.f;
}

#define GLDS16(g, l)                                                               \
    __builtin_amdgcn_global_load_lds((const __attribute__((address_space(1))) void*)(g), \
                                     (__attribute__((address_space(3))) void*)(l), 16, 0, 0)

// ---------------------------------------------------------------------------
// fp32 -> bf16 straight convert (x). Each thread: 8 elements.
// ---------------------------------------------------------------------------
__global__ __launch_bounds__(256) void cvt_x(const float* __restrict__ src,
                                             u16* __restrict__ dst) {
    int i = blockIdx.x * 256 + threadIdx.x;
    const float4* s = (const float4*)src + (size_t)i * 2;
    float4 a = s[0], b = s[1];
    u16x8 o;
    o[0] = f2bf(a.x); o[1] = f2bf(a.y); o[2] = f2bf(a.z); o[3] = f2bf(a.w);
    o[4] = f2bf(b.x); o[5] = f2bf(b.y); o[6] = f2bf(b.z); o[7] = f2bf(b.w);
    *(u16x8*)(dst + (size_t)i * 8) = o;
}

// ---------------------------------------------------------------------------
// Transpose-convert: src fp32 [2048 k][C n] -> dst bf16 [C n][2048 k].
// 32x32 LDS tile.
// ---------------------------------------------------------------------------
__global__ __launch_bounds__(256) void tcvt(const float* __restrict__ src,
                                            u16* __restrict__ dst, int C) {
    __shared__ u16 tile[32][33];
    const int t = threadIdx.x;
    const int bx = blockIdx.x, by = blockIdx.y;   // bx: n-tile, by: k-tile
    const int tr = t >> 3, tc = (t & 7) << 2;
    float4 f = *(const float4*)&src[(size_t)(by * 32 + tr) * C + bx * 32 + tc];
    tile[tr][tc + 0] = f2bf(f.x); tile[tr][tc + 1] = f2bf(f.y);
    tile[tr][tc + 2] = f2bf(f.z); tile[tr][tc + 3] = f2bf(f.w);
    __syncthreads();
    u16x4 o;
    o[0] = tile[tc + 0][tr]; o[1] = tile[tc + 1][tr];
    o[2] = tile[tc + 2][tr]; o[3] = tile[tc + 3][tr];
    *(u16x4*)&dst[(size_t)(bx * 32 + tr) * 2048 + by * 32 + tc] = o;
}

// ---------------------------------------------------------------------------
// m97-style GEMM: C[M x N] = A[M x 2048] * Bt[N x 2048]^T, bf16 inputs.
// 128x128 tile, BK=32, 4 waves (2x2 of 64x64), global_load_lds width-16.
// MODE 0: segmented qkv epilogue (q bf16, k bf16, v bf16 TRANSPOSED [dkv][4096])
// MODE 1: fp32 C, N=2048
// ---------------------------------------------------------------------------
template <int MODE>
__global__ __launch_bounds__(256) void gemm2(const u16* __restrict__ A,
                                             const u16* __restrict__ Bt,
                                             u16* __restrict__ oq, u16* __restrict__ ok,
                                             u16* __restrict__ ov, float* __restrict__ of) {
    __shared__ u16 As[128 * 32];
    __shared__ u16 Bs[128 * 32];
    const int t = threadIdx.x, w = t >> 6, lane = t & 63;
    const int l15 = lane & 15, quad = lane >> 4;
    const int m0 = blockIdx.y << 7, n0 = blockIdx.x << 7;
    const int K = 2048;
    const int c0 = w * 2, c1 = c0 + 1;
    const int ar0 = c0 * 16 + (lane >> 2), ar1 = c1 * 16 + (lane >> 2);
    const int ac = (lane & 3) << 3;
    const u16* Ap0 = A + (size_t)(m0 + ar0) * K + ac;
    const u16* Ap1 = A + (size_t)(m0 + ar1) * K + ac;
    const u16* Bp0 = Bt + (size_t)(n0 + ar0) * K + ac;
    const u16* Bp1 = Bt + (size_t)(n0 + ar1) * K + ac;
    const int wm = (w >> 1) << 6, wn = (w & 1) << 6;

    f32x4 acc[4][4] = {};

    for (int k0 = 0; k0 < K; k0 += 32) {
        GLDS16(Ap0 + k0, &As[c0 * 512]);
        GLDS16(Ap1 + k0, &As[c1 * 512]);
        GLDS16(Bp0 + k0, &Bs[c0 * 512]);
        GLDS16(Bp1 + k0, &Bs[c1 * 512]);
        __syncthreads();
        bf16x8 a[4], bfr[4];
#pragma unroll
        for (int mt = 0; mt < 4; ++mt)
            a[mt] = *(bf16x8*)&As[(wm + mt * 16 + l15) * 32 + quad * 8];
#pragma unroll
        for (int nt = 0; nt < 4; ++nt)
            bfr[nt] = *(bf16x8*)&Bs[(wn + nt * 16 + l15) * 32 + quad * 8];
#pragma unroll
        for (int mt = 0; mt < 4; ++mt)
#pragma unroll
            for (int nt = 0; nt < 4; ++nt)
                acc[mt][nt] = __builtin_amdgcn_mfma_f32_16x16x32_bf16(a[mt], bfr[nt], acc[mt][nt], 0, 0, 0);
        __syncthreads();
    }

#pragma unroll
    for (int mt = 0; mt < 4; ++mt)
#pragma unroll
        for (int nt = 0; nt < 4; ++nt)
#pragma unroll
            for (int r = 0; r < 4; ++r) {
                int row = m0 + wm + mt * 16 + quad * 4 + r;
                int col = n0 + wn + nt * 16 + l15;
                float vv = acc[mt][nt][r];
                if constexpr (MODE == 0) {
                    if (col < 2048)
                        oq[(size_t)row * 2048 + col] = f2bf(vv);
                    else if (col < 2560)
                        ok[(size_t)row * 512 + (col - 2048)] = f2bf(vv);
                    else
                        ov[(size_t)(col - 2560) * 4096 + row] = f2bf(vv);  // V transposed
                } else {
                    of[(size_t)row * 2048 + col] = vv;
                }
            }
}

// ---------------------------------------------------------------------------
// RoPE in place (one thread = one 64-d head vector).
// ---------------------------------------------------------------------------
__global__ __launch_bounds__(256) void rope_k(u16* __restrict__ buf, int hshift) {
    const int idx = blockIdx.x * 256 + threadIdx.x;
    const int row = idx >> hshift;
    const int tt = row & 2047;
    u16* p = buf + (size_t)idx * 64;
    float x[64];
#pragma unroll
    for (int i = 0; i < 8; ++i) {
        u16x8 v = *(const u16x8*)(p + i * 8);
#pragma unroll
        for (int j = 0; j < 8; ++j) x[i * 8 + j] = bf2f(v[j]);
    }
    float cs[32], sn[32];
    const float ft = (float)tt;
#pragma unroll
    for (int i = 0; i < 32; ++i) {
        float invf = exp2f(-0.4152410118609253f * (float)i);
        float ang = ft * invf;
        sn[i] = sinf(ang);
        cs[i] = cosf(ang);
    }
#pragma unroll
    for (int i = 0; i < 8; ++i) {
        u16x8 v;
#pragma unroll
        for (int j = 0; j < 8; ++j) {
            int d = i * 8 + j;
            float rh = (d < 32) ? -x[2 * d + 1] : x[2 * (d - 32)];
            v[j] = f2bf(x[d] * cs[d >> 1] + rh * sn[d >> 1]);
        }
        *(u16x8*)(p + i * 8) = v;
    }
}

// ---------------------------------------------------------------------------
// Flash attention v2: block = (bx, kvh, b); qb = b ? 31-bx : bx (load balance).
// 4 waves = the 4 Q-heads sharing the KV head. K/V staged once per k-tile.
// vT input is pre-transposed: [512 kv-dim][4096 tokens].
// ---------------------------------------------------------------------------
__global__ __launch_bounds__(256, 2) void attn2(const u16* __restrict__ q,
                                                const u16* __restrict__ k,
                                                const u16* __restrict__ vT,
                                                u16* __restrict__ att) {
    __shared__ u16 Ks[64 * 72];     // [key][d]
    __shared__ u16 Vt[64 * 72];     // [d][key]
    __shared__ u16 Ps[4][64 * 72];  // per-wave [q][key]

    const int t = threadIdx.x, w = t >> 6, lane = t & 63;
    const int l15 = lane & 15, quad = lane >> 4;
    const int kvh = blockIdx.y, b = blockIdx.z;
    const int qb = b ? (31 - (int)blockIdx.x) : (int)blockIdx.x;
    const int h = kvh * 4 + w;
    const size_t rowbase = (size_t)b * 2048;
    const int sr = t >> 2, sd = (t & 3) << 4;

    bf16x8 aq[4][2];
#pragma unroll
    for (int mt = 0; mt < 4; ++mt)
#pragma unroll
        for (int kc = 0; kc < 2; ++kc)
            aq[mt][kc] = *(const bf16x8*)&q[(rowbase + qb * 64 + mt * 16 + l15) * 2048 + h * 64 + kc * 32 + quad * 8];

    f32x4 acc[4][4] = {};
    float m_i[4][4], l_i[4][4];
#pragma unroll
    for (int mt = 0; mt < 4; ++mt)
#pragma unroll
        for (int r = 0; r < 4; ++r) { m_i[mt][r] = -INFINITY; l_i[mt][r] = 0.f; }

    for (int kb = 0; kb <= qb; ++kb) {
        {   // stage K [key][d] and V^T [d][key], both vectorized
            const u16* kp = &k[(rowbase + kb * 64 + sr) * 512 + kvh * 64 + sd];
            *(u16x8*)&Ks[sr * 72 + sd]     = *(const u16x8*)kp;
            *(u16x8*)&Ks[sr * 72 + sd + 8] = *(const u16x8*)(kp + 8);
            const u16* vp = &vT[(size_t)(kvh * 64 + sr) * 4096 + rowbase + kb * 64 + sd];
            *(u16x8*)&Vt[sr * 72 + sd]     = *(const u16x8*)vp;
            *(u16x8*)&Vt[sr * 72 + sd + 8] = *(const u16x8*)(vp + 8);
        }
        __syncthreads();

        bf16x8 bv[4][2];
#pragma unroll
        for (int dt = 0; dt < 4; ++dt)
#pragma unroll
            for (int kc = 0; kc < 2; ++kc)
                bv[dt][kc] = *(bf16x8*)&Vt[(dt * 16 + l15) * 72 + kc * 32 + quad * 8];

        const bool diag = (kb == qb);
#pragma unroll
        for (int mt = 0; mt < 4; ++mt) {
            f32x4 s[4] = {};
#pragma unroll
            for (int nt = 0; nt < 4; ++nt) {
                bf16x8 bk0 = *(bf16x8*)&Ks[(nt * 16 + l15) * 72 + quad * 8];
                bf16x8 bk1 = *(bf16x8*)&Ks[(nt * 16 + l15) * 72 + 32 + quad * 8];
                s[nt] = __builtin_amdgcn_mfma_f32_16x16x32_bf16(aq[mt][0], bk0, s[nt], 0, 0, 0);
                s[nt] = __builtin_amdgcn_mfma_f32_16x16x32_bf16(aq[mt][1], bk1, s[nt], 0, 0, 0);
            }
            float al[4];
#pragma unroll
            for (int r = 0; r < 4; ++r) {
                float sv[4];
#pragma unroll
                for (int nt = 0; nt < 4; ++nt) sv[nt] = s[nt][r] * 0.125f;
                if (diag) {
                    int qr = mt * 16 + quad * 4 + r;
#pragma unroll
                    for (int nt = 0; nt < 4; ++nt)
                        if (nt * 16 + l15 > qr) sv[nt] = -INFINITY;
                }
                float mx = fmaxf(fmaxf(sv[0], sv[1]), fmaxf(sv[2], sv[3]));
#pragma unroll
                for (int off = 1; off < 16; off <<= 1) mx = fmaxf(mx, __shfl_xor(mx, off, 16));
                float mnew = fmaxf(m_i[mt][r], mx);
                float sum = 0.f;
#pragma unroll
                for (int nt = 0; nt < 4; ++nt) { sv[nt] = __expf(sv[nt] - mnew); sum += sv[nt]; }
#pragma unroll
                for (int off = 1; off < 16; off <<= 1) sum += __shfl_xor(sum, off, 16);
                float a = __expf(m_i[mt][r] - mnew);
                l_i[mt][r] = l_i[mt][r] * a + sum;
                m_i[mt][r] = mnew;
                al[r] = a;
#pragma unroll
                for (int nt = 0; nt < 4; ++nt)
                    Ps[w][(mt * 16 + quad * 4 + r) * 72 + nt * 16 + l15] = f2bf(sv[nt]);
            }
#pragma unroll
            for (int dt = 0; dt < 4; ++dt)
#pragma unroll
                for (int r = 0; r < 4; ++r) acc[mt][dt][r] *= al[r];

            bf16x8 ap0 = *(bf16x8*)&Ps[w][(mt * 16 + l15) * 72 + quad * 8];
            bf16x8 ap1 = *(bf16x8*)&Ps[w][(mt * 16 + l15) * 72 + 32 + quad * 8];
#pragma unroll
            for (int dt = 0; dt < 4; ++dt) {
                acc[mt][dt] = __builtin_amdgcn_mfma_f32_16x16x32_bf16(ap0, bv[dt][0], acc[mt][dt], 0, 0, 0);
                acc[mt][dt] = __builtin_amdgcn_mfma_f32_16x16x32_bf16(ap1, bv[dt][1], acc[mt][dt], 0, 0, 0);
            }
        }
        __syncthreads();
    }

#pragma unroll
    for (int mt = 0; mt < 4; ++mt)
#pragma unroll
        for (int r = 0; r < 4; ++r) {
            float inv = 1.0f / l_i[mt][r];
            size_t row = rowbase + qb * 64 + mt * 16 + quad * 4 + r;
#pragma unroll
            for (int dt = 0; dt < 4; ++dt)
                att[row * 2048 + h * 64 + dt * 16 + l15] = f2bf(acc[mt][dt][r] * inv);
        }
}

// ---------------------------------------------------------------------------
extern "C" void kernel_launch(void* const* d_in, const int* in_sizes, int n_in,
                              void* d_out, int out_size, void* d_ws, size_t ws_size,
                              hipStream_t stream) {
    const float* x  = (const float*)d_in[0];
    const float* Wq = (const float*)d_in[2];
    const float* Wk = (const float*)d_in[3];
    const float* Wv = (const float*)d_in[4];
    const float* Wo = (const float*)d_in[5];
    float* out = (float*)d_out;

    // xb (bf16 x) lives in the FIRST HALF of d_out (dead before out-proj writes).
    u16* xb = (u16*)d_out;                                   // 4096x2048 bf16 (16.78 MB of 33.55)

    // ws layout (41.94 MB total — proven size):
    u16* q     = (u16*)d_ws;                                 // [0,      16.78M)  4096x2048
    u16* kk    = q + (size_t)4096 * 2048;                    // [16.78,  20.97M)  4096x512
    u16* vt    = kk + (size_t)4096 * 512;                    // [20.97,  25.17M)  512x4096 (transposed V)
    u16* wqkvt = vt + (size_t)4096 * 512;                    // [25.17,  37.75M)  3072x2048, dead after QKV gemm
    u16* att   = wqkvt;                                      // [25.17,  41.94M)  4096x2048 (aliases wqkvt + 4.2MB spare)
    u16* wot   = kk;                                         // [16.78,  25.17M)  2048x2048 (aliases dead kk+vt, built after attn)

    // 1. convert x -> bf16
    cvt_x<<<4096, 256, 0, stream>>>(x, xb);
    // 2. transpose-convert Wq/Wk/Wv -> Wqkv^T [n][k]
    tcvt<<<dim3(64, 64), 256, 0, stream>>>(Wq, wqkvt, 2048);
    tcvt<<<dim3(16, 64), 256, 0, stream>>>(Wk, wqkvt + (size_t)2048 * 2048, 512);
    tcvt<<<dim3(16, 64), 256, 0, stream>>>(Wv, wqkvt + (size_t)2560 * 2048, 512);
    // 3. fused QKV gemm (M=4096, N=3072), V written transposed
    gemm2<0><<<dim3(24, 32), 256, 0, stream>>>(xb, wqkvt, q, kk, vt, nullptr);
    // 4. rope q (32 heads), k (8 heads)
    rope_k<<<512, 256, 0, stream>>>(q, 5);
    rope_k<<<128, 256, 0, stream>>>(kk, 3);
    // 5. attention (att aliases the now-dead wqkvt)
    attn2<<<dim3(32, 8, 2), 256, 0, stream>>>(q, kk, vt, att);
    // 6. transpose-convert Wo -> Wo^T (into now-dead kk+vt region)
    tcvt<<<dim3(64, 64), 256, 0, stream>>>(Wo, wot, 2048);
    // 7. out projection (fp32 out)
    gemm2<1><<<dim3(16, 32), 256, 0, stream>>>(att, wot, nullptr, nullptr, nullptr, out);
}

// Round 3
// 387.215 us; speedup vs baseline: 2.4587x; 1.3902x over previous
//
#include <hip/hip_runtime.h>
#include <cstdint>
#include <cstddef>

typedef unsigned short u16;
typedef __attribute__((ext_vector_type(8))) short bf16x8;
typedef __attribute__((ext_vector_type(8))) unsigned short u16x8;
typedef __attribute__((ext_vector_type(4))) unsigned short u16x4;
typedef __attribute__((ext_vector_type(4))) float f32x4;

__device__ __forceinline__ unsigned short f2bf(float f) {
    union { float f; uint32_t u; } c; c.f = f;
    uint32_t u = c.u + 0x7fffu + ((c.u >> 16) & 1u);
    return (unsigned short)(u >> 16);
}
__device__ __forceinline__ float bf2f(unsigned short h) {
    union { uint32_t u; float f; } c; c.u = ((uint32_t)h) << 16;
    return c.f;
}
// pack two floats -> two bf16 (round-to-nearest-ish) in one dword
__device__ __forceinline__ uint32_t pkbf(float a, float b) {
    union { float f; uint32_t u; } x, y; x.f = a; y.f = b;
    return ((x.u + 0x8000u) >> 16) | ((y.u + 0x8000u) & 0xFFFF0000u);
}

#define GLDS16(g, l)                                                               \
    __builtin_amdgcn_global_load_lds((const __attribute__((address_space(1))) void*)(g), \
                                     (__attribute__((address_space(3))) void*)(l), 16, 0, 0)

// ---------------------------------------------------------------------------
// fp32 -> bf16 straight convert (x). Each thread: 8 elements.
// ---------------------------------------------------------------------------
__global__ __launch_bounds__(256) void cvt_x(const float* __restrict__ src,
                                             u16* __restrict__ dst) {
    int i = blockIdx.x * 256 + threadIdx.x;
    const float4* s = (const float4*)src + (size_t)i * 2;
    float4 a = s[0], b = s[1];
    u16x8 o;
    o[0] = f2bf(a.x); o[1] = f2bf(a.y); o[2] = f2bf(a.z); o[3] = f2bf(a.w);
    o[4] = f2bf(b.x); o[5] = f2bf(b.y); o[6] = f2bf(b.z); o[7] = f2bf(b.w);
    *(u16x8*)(dst + (size_t)i * 8) = o;
}

// ---------------------------------------------------------------------------
// Transpose-convert: src fp32 [2048 k][C n] -> dst bf16 [C n][2048 k].
// ---------------------------------------------------------------------------
__global__ __launch_bounds__(256) void tcvt(const float* __restrict__ src,
                                            u16* __restrict__ dst, int C) {
    __shared__ u16 tile[32][33];
    const int t = threadIdx.x;
    const int bx = blockIdx.x, by = blockIdx.y;
    const int tr = t >> 3, tc = (t & 7) << 2;
    float4 f = *(const float4*)&src[(size_t)(by * 32 + tr) * C + bx * 32 + tc];
    tile[tr][tc + 0] = f2bf(f.x); tile[tr][tc + 1] = f2bf(f.y);
    tile[tr][tc + 2] = f2bf(f.z); tile[tr][tc + 3] = f2bf(f.w);
    __syncthreads();
    u16x4 o;
    o[0] = tile[tc + 0][tr]; o[1] = tile[tc + 1][tr];
    o[2] = tile[tc + 2][tr]; o[3] = tile[tc + 3][tr];
    *(u16x4*)&dst[(size_t)(bx * 32 + tr) * 2048 + by * 32 + tc] = o;
}

// ---------------------------------------------------------------------------
// m97-style GEMM: C[M x N] = A[M x 2048] * Bt[N x 2048]^T, bf16 inputs.
// MODE 0: segmented qkv epilogue (q, k, v-transposed). MODE 1: fp32 C, N=2048.
// ---------------------------------------------------------------------------
template <int MODE>
__global__ __launch_bounds__(256) void gemm2(const u16* __restrict__ A,
                                             const u16* __restrict__ Bt,
                                             u16* __restrict__ oq, u16* __restrict__ ok,
                                             u16* __restrict__ ov, float* __restrict__ of) {
    __shared__ u16 As[128 * 32];
    __shared__ u16 Bs[128 * 32];
    const int t = threadIdx.x, w = t >> 6, lane = t & 63;
    const int l15 = lane & 15, quad = lane >> 4;
    const int m0 = blockIdx.y << 7, n0 = blockIdx.x << 7;
    const int K = 2048;
    const int c0 = w * 2, c1 = c0 + 1;
    const int ar0 = c0 * 16 + (lane >> 2), ar1 = c1 * 16 + (lane >> 2);
    const int ac = (lane & 3) << 3;
    const u16* Ap0 = A + (size_t)(m0 + ar0) * K + ac;
    const u16* Ap1 = A + (size_t)(m0 + ar1) * K + ac;
    const u16* Bp0 = Bt + (size_t)(n0 + ar0) * K + ac;
    const u16* Bp1 = Bt + (size_t)(n0 + ar1) * K + ac;
    const int wm = (w >> 1) << 6, wn = (w & 1) << 6;

    f32x4 acc[4][4] = {};

    for (int k0 = 0; k0 < K; k0 += 32) {
        GLDS16(Ap0 + k0, &As[c0 * 512]);
        GLDS16(Ap1 + k0, &As[c1 * 512]);
        GLDS16(Bp0 + k0, &Bs[c0 * 512]);
        GLDS16(Bp1 + k0, &Bs[c1 * 512]);
        __syncthreads();
        bf16x8 a[4], bfr[4];
#pragma unroll
        for (int mt = 0; mt < 4; ++mt)
            a[mt] = *(bf16x8*)&As[(wm + mt * 16 + l15) * 32 + quad * 8];
#pragma unroll
        for (int nt = 0; nt < 4; ++nt)
            bfr[nt] = *(bf16x8*)&Bs[(wn + nt * 16 + l15) * 32 + quad * 8];
#pragma unroll
        for (int mt = 0; mt < 4; ++mt)
#pragma unroll
            for (int nt = 0; nt < 4; ++nt)
                acc[mt][nt] = __builtin_amdgcn_mfma_f32_16x16x32_bf16(a[mt], bfr[nt], acc[mt][nt], 0, 0, 0);
        __syncthreads();
    }

#pragma unroll
    for (int mt = 0; mt < 4; ++mt)
#pragma unroll
        for (int nt = 0; nt < 4; ++nt)
#pragma unroll
            for (int r = 0; r < 4; ++r) {
                int row = m0 + wm + mt * 16 + quad * 4 + r;
                int col = n0 + wn + nt * 16 + l15;
                float vv = acc[mt][nt][r];
                if constexpr (MODE == 0) {
                    if (col < 2048)
                        oq[(size_t)row * 2048 + col] = f2bf(vv);
                    else if (col < 2560)
                        ok[(size_t)row * 512 + (col - 2048)] = f2bf(vv);
                    else
                        ov[(size_t)(col - 2560) * 4096 + row] = f2bf(vv);  // V transposed
                } else {
                    of[(size_t)row * 2048 + col] = vv;
                }
            }
}

// ---------------------------------------------------------------------------
// RoPE in place (one thread = one 64-d head vector).
// ---------------------------------------------------------------------------
__global__ __launch_bounds__(256) void rope_k(u16* __restrict__ buf, int hshift) {
    const int idx = blockIdx.x * 256 + threadIdx.x;
    const int row = idx >> hshift;
    const int tt = row & 2047;
    u16* p = buf + (size_t)idx * 64;
    float x[64];
#pragma unroll
    for (int i = 0; i < 8; ++i) {
        u16x8 v = *(const u16x8*)(p + i * 8);
#pragma unroll
        for (int j = 0; j < 8; ++j) x[i * 8 + j] = bf2f(v[j]);
    }
    float cs[32], sn[32];
    const float ft = (float)tt;
#pragma unroll
    for (int i = 0; i < 32; ++i) {
        float invf = exp2f(-0.4152410118609253f * (float)i);
        float ang = ft * invf;
        sn[i] = sinf(ang);
        cs[i] = cosf(ang);
    }
#pragma unroll
    for (int i = 0; i < 8; ++i) {
        u16x8 v;
#pragma unroll
        for (int j = 0; j < 8; ++j) {
            int d = i * 8 + j;
            float rh = (d < 32) ? -x[2 * d + 1] : x[2 * (d - 32)];
            v[j] = f2bf(x[d] * cs[d >> 1] + rh * sn[d >> 1]);
        }
        *(u16x8*)(p + i * 8) = v;
    }
}

// ---------------------------------------------------------------------------
// Flash attention v3 — S^T formulation (lane = one query column).
// Block = (bx 0..31, kvh, b), 4 waves = 4 Q-heads of the KV group.
// Processes q-groups g=bx and g=63-bx (32 rows each) => uniform 33 k-tiles.
// S^T = K·Q^T  (lane: key=kt*16+quad*4+r, q=l15) -> softmax needs only
// 2 shuffles/reduction; alpha is a per-lane scalar for the O^T accumulator.
// O^T = V^T · P^T, acc C-layout [d=quad*4+r][q=l15].
// ---------------------------------------------------------------------------
__global__ __launch_bounds__(256, 2) void attn3(const u16* __restrict__ q,
                                                const u16* __restrict__ k,
                                                const u16* __restrict__ vT,
                                                u16* __restrict__ att) {
    __shared__ u16 Ks[64 * 72];     // [key][d]
    __shared__ u16 Vt[64 * 72];     // [d][key]
    __shared__ u16 Pw[4][16 * 72];  // per-wave P^T staging: [q][key]

    const int t = threadIdx.x, w = t >> 6, lane = t & 63;
    const int l15 = lane & 15, quad = lane >> 4;
    const int bx = blockIdx.x, kvh = blockIdx.y, b = blockIdx.z;
    const int h = kvh * 4 + w;
    const size_t rowbase = (size_t)b * 2048;
    const int sr = t >> 2, sd = (t & 3) << 4;
    u16* Pq = &Pw[w][0];

    const float SC = 0.125f * 1.4426950408889634f;  // 1/sqrt(64) * log2(e)

    for (int grp = 0; grp < 2; ++grp) {
        const int g = grp ? (63 - bx) : bx;
        const int qbase = g * 32;
        const int ntiles = (g >> 1) + 1;

        // Q B-frags: B[n=q=l15][k=d], per mt (16 q) and d-chunk
        bf16x8 aq[2][2];
#pragma unroll
        for (int mt = 0; mt < 2; ++mt)
#pragma unroll
            for (int kc = 0; kc < 2; ++kc)
                aq[mt][kc] = *(const bf16x8*)&q[(rowbase + qbase + mt * 16 + l15) * 2048 +
                                               h * 64 + kc * 32 + quad * 8];

        f32x4 acc[2][4] = {};
        float m_i[2] = {-INFINITY, -INFINITY};
        float l_i[2] = {0.f, 0.f};

        for (int kb = 0; kb < ntiles; ++kb) {
            {   // stage K [key][d] and V^T [d][key]
                const u16* kp = &k[(rowbase + kb * 64 + sr) * 512 + kvh * 64 + sd];
                *(u16x8*)&Ks[sr * 72 + sd]     = *(const u16x8*)kp;
                *(u16x8*)&Ks[sr * 72 + sd + 8] = *(const u16x8*)(kp + 8);
                const u16* vp = &vT[(size_t)(kvh * 64 + sr) * 4096 + rowbase + kb * 64 + sd];
                *(u16x8*)&Vt[sr * 72 + sd]     = *(const u16x8*)vp;
                *(u16x8*)&Vt[sr * 72 + sd + 8] = *(const u16x8*)(vp + 8);
            }
            __syncthreads();

            // hoisted fragments (shared by both mt)
            bf16x8 ak[4][2], av[4][2];
#pragma unroll
            for (int kt = 0; kt < 4; ++kt)
#pragma unroll
                for (int kc = 0; kc < 2; ++kc)
                    ak[kt][kc] = *(bf16x8*)&Ks[(kt * 16 + l15) * 72 + kc * 32 + quad * 8];
#pragma unroll
            for (int dt = 0; dt < 4; ++dt)
#pragma unroll
                for (int kc = 0; kc < 2; ++kc)
                    av[dt][kc] = *(bf16x8*)&Vt[(dt * 16 + l15) * 72 + kc * 32 + quad * 8];

            const bool diag = (kb == ntiles - 1);

#pragma unroll
            for (int mt = 0; mt < 2; ++mt) {
                // S^T: lane(key = kt*16+quad*4+r, q = l15)
                f32x4 st[4] = {};
#pragma unroll
                for (int kt = 0; kt < 4; ++kt) {
                    st[kt] = __builtin_amdgcn_mfma_f32_16x16x32_bf16(ak[kt][0], aq[mt][0], st[kt], 0, 0, 0);
                    st[kt] = __builtin_amdgcn_mfma_f32_16x16x32_bf16(ak[kt][1], aq[mt][1], st[kt], 0, 0, 0);
                }
                float sv[16];
#pragma unroll
                for (int kt = 0; kt < 4; ++kt)
#pragma unroll
                    for (int r = 0; r < 4; ++r) sv[kt * 4 + r] = st[kt][r] * SC;
                if (diag) {
                    const int qg = qbase + mt * 16 + l15;
#pragma unroll
                    for (int kt = 0; kt < 4; ++kt)
#pragma unroll
                        for (int r = 0; r < 4; ++r) {
                            int key = kb * 64 + kt * 16 + quad * 4 + r;
                            if (key > qg) sv[kt * 4 + r] = -INFINITY;
                        }
                }
                float mx = sv[0];
#pragma unroll
                for (int i = 1; i < 16; ++i) mx = fmaxf(mx, sv[i]);
                mx = fmaxf(mx, __shfl_xor(mx, 16));
                mx = fmaxf(mx, __shfl_xor(mx, 32));
                float mnew = fmaxf(m_i[mt], mx);
                float sum = 0.f;
#pragma unroll
                for (int i = 0; i < 16; ++i) {
                    sv[i] = __builtin_amdgcn_exp2f(sv[i] - mnew);
                    sum += sv[i];
                }
                sum += __shfl_xor(sum, 16);
                sum += __shfl_xor(sum, 32);
                float alpha = __builtin_amdgcn_exp2f(m_i[mt] - mnew);
                l_i[mt] = l_i[mt] * alpha + sum;
                m_i[mt] = mnew;

                // pack P^T into per-wave LDS: Pq[q=l15][key], 8B per kt
#pragma unroll
                for (int kt = 0; kt < 4; ++kt) {
                    uint32_t d0 = pkbf(sv[kt * 4 + 0], sv[kt * 4 + 1]);
                    uint32_t d1 = pkbf(sv[kt * 4 + 2], sv[kt * 4 + 3]);
                    uint2 uu; uu.x = d0; uu.y = d1;
                    *(uint2*)&Pq[l15 * 72 + kt * 16 + quad * 4] = uu;
                }
                // read back as B-frag: B[n=q=l15][k=key=quad*8+j]
                bf16x8 bp0 = *(bf16x8*)&Pq[l15 * 72 + quad * 8];
                bf16x8 bp1 = *(bf16x8*)&Pq[l15 * 72 + 32 + quad * 8];

#pragma unroll
                for (int dt = 0; dt < 4; ++dt) {
#pragma unroll
                    for (int r = 0; r < 4; ++r) acc[mt][dt][r] *= alpha;
                    acc[mt][dt] = __builtin_amdgcn_mfma_f32_16x16x32_bf16(av[dt][0], bp0, acc[mt][dt], 0, 0, 0);
                    acc[mt][dt] = __builtin_amdgcn_mfma_f32_16x16x32_bf16(av[dt][1], bp1, acc[mt][dt], 0, 0, 0);
                }
            }
            __syncthreads();
        }

        // epilogue: O^T lane(d = dt*16+quad*4+r, q = l15)
#pragma unroll
        for (int mt = 0; mt < 2; ++mt) {
            float inv = 1.0f / l_i[mt];
            size_t row = rowbase + qbase + mt * 16 + l15;
#pragma unroll
            for (int dt = 0; dt < 4; ++dt) {
                uint2 uu;
                uu.x = pkbf(acc[mt][dt][0] * inv, acc[mt][dt][1] * inv);
                uu.y = pkbf(acc[mt][dt][2] * inv, acc[mt][dt][3] * inv);
                *(uint2*)&att[row * 2048 + h * 64 + dt * 16 + quad * 4] = uu;
            }
        }
    }
}

// ---------------------------------------------------------------------------
extern "C" void kernel_launch(void* const* d_in, const int* in_sizes, int n_in,
                              void* d_out, int out_size, void* d_ws, size_t ws_size,
                              hipStream_t stream) {
    const float* x  = (const float*)d_in[0];
    const float* Wq = (const float*)d_in[2];
    const float* Wk = (const float*)d_in[3];
    const float* Wv = (const float*)d_in[4];
    const float* Wo = (const float*)d_in[5];
    float* out = (float*)d_out;

    u16* xb = (u16*)d_out;                                   // bf16 x in d_out (dead before final write)

    u16* q     = (u16*)d_ws;                                 // 4096x2048
    u16* kk    = q + (size_t)4096 * 2048;                    // 4096x512
    u16* vt    = kk + (size_t)4096 * 512;                    // 512x4096 (V^T)
    u16* wqkvt = vt + (size_t)4096 * 512;                    // 3072x2048 (dead after QKV gemm)
    u16* att   = wqkvt;                                      // 4096x2048 aliases dead wqkvt
    u16* wot   = kk;                                         // 2048x2048 aliases dead kk+vt (after attn)

    cvt_x<<<4096, 256, 0, stream>>>(x, xb);
    tcvt<<<dim3(64, 64), 256, 0, stream>>>(Wq, wqkvt, 2048);
    tcvt<<<dim3(16, 64), 256, 0, stream>>>(Wk, wqkvt + (size_t)2048 * 2048, 512);
    tcvt<<<dim3(16, 64), 256, 0, stream>>>(Wv, wqkvt + (size_t)2560 * 2048, 512);
    gemm2<0><<<dim3(24, 32), 256, 0, stream>>>(xb, wqkvt, q, kk, vt, nullptr);
    rope_k<<<512, 256, 0, stream>>>(q, 5);
    rope_k<<<128, 256, 0, stream>>>(kk, 3);
    attn3<<<dim3(32, 8, 2), 256, 0, stream>>>(q, kk, vt, att);
    tcvt<<<dim3(64, 64), 256, 0, stream>>>(Wo, wot, 2048);
    gemm2<1><<<dim3(16, 32), 256, 0, stream>>>(att, wot, nullptr, nullptr, nullptr, out);
}

// Round 4
// 333.861 us; speedup vs baseline: 2.8517x; 1.1598x over previous
//
#include <hip/hip_runtime.h>
#include <cstdint>
#include <cstddef>

typedef unsigned short u16;
typedef __attribute__((ext_vector_type(8))) short bf16x8;
typedef __attribute__((ext_vector_type(8))) unsigned short u16x8;
typedef __attribute__((ext_vector_type(4))) unsigned short u16x4;
typedef __attribute__((ext_vector_type(4))) float f32x4;

__device__ __forceinline__ unsigned short f2bf(float f) {
    union { float f; uint32_t u; } c; c.f = f;
    uint32_t u = c.u + 0x7fffu + ((c.u >> 16) & 1u);
    return (unsigned short)(u >> 16);
}
__device__ __forceinline__ float bf2f(unsigned short h) {
    union { uint32_t u; float f; } c; c.u = ((uint32_t)h) << 16;
    return c.f;
}
__device__ __forceinline__ uint32_t pkbf(float a, float b) {
    union { float f; uint32_t u; } x, y; x.f = a; y.f = b;
    return ((x.u + 0x8000u) >> 16) | ((y.u + 0x8000u) & 0xFFFF0000u);
}

#define GLDS16(g, l)                                                               \
    __builtin_amdgcn_global_load_lds((const __attribute__((address_space(1))) void*)(g), \
                                     (__attribute__((address_space(3))) void*)(l), 16, 0, 0)

// ---------------------------------------------------------------------------
// fp32 -> bf16 straight convert (x).
// ---------------------------------------------------------------------------
__global__ __launch_bounds__(256) void cvt_x(const float* __restrict__ src,
                                             u16* __restrict__ dst) {
    int i = blockIdx.x * 256 + threadIdx.x;
    const float4* s = (const float4*)src + (size_t)i * 2;
    float4 a = s[0], b = s[1];
    u16x8 o;
    o[0] = f2bf(a.x); o[1] = f2bf(a.y); o[2] = f2bf(a.z); o[3] = f2bf(a.w);
    o[4] = f2bf(b.x); o[5] = f2bf(b.y); o[6] = f2bf(b.z); o[7] = f2bf(b.w);
    *(u16x8*)(dst + (size_t)i * 8) = o;
}

// ---------------------------------------------------------------------------
// Transpose-convert: src fp32 [2048 k][C n] -> dst bf16 [C n][2048 k].
// ---------------------------------------------------------------------------
__global__ __launch_bounds__(256) void tcvt(const float* __restrict__ src,
                                            u16* __restrict__ dst, int C) {
    __shared__ u16 tile[32][33];
    const int t = threadIdx.x;
    const int bx = blockIdx.x, by = blockIdx.y;
    const int tr = t >> 3, tc = (t & 7) << 2;
    float4 f = *(const float4*)&src[(size_t)(by * 32 + tr) * C + bx * 32 + tc];
    tile[tr][tc + 0] = f2bf(f.x); tile[tr][tc + 1] = f2bf(f.y);
    tile[tr][tc + 2] = f2bf(f.z); tile[tr][tc + 3] = f2bf(f.w);
    __syncthreads();
    u16x4 o;
    o[0] = tile[tc + 0][tr]; o[1] = tile[tc + 1][tr];
    o[2] = tile[tc + 2][tr]; o[3] = tile[tc + 3][tr];
    *(u16x4*)&dst[(size_t)(bx * 32 + tr) * 2048 + by * 32 + tc] = o;
}

// Merged transpose-convert for Wq|Wk|Wv -> wqkvt (one launch).
__global__ __launch_bounds__(256) void tcvt3(const float* __restrict__ Wq,
                                             const float* __restrict__ Wk,
                                             const float* __restrict__ Wv,
                                             u16* __restrict__ dst) {
    __shared__ u16 tile[32][33];
    const int t = threadIdx.x;
    const int bxg = blockIdx.x, by = blockIdx.y;
    const float* src; int C, nb; u16* dbase;
    if (bxg < 64)      { src = Wq; C = 2048; nb = bxg;      dbase = dst; }
    else if (bxg < 80) { src = Wk; C = 512;  nb = bxg - 64; dbase = dst + (size_t)2048 * 2048; }
    else               { src = Wv; C = 512;  nb = bxg - 80; dbase = dst + (size_t)2560 * 2048; }
    const int tr = t >> 3, tc = (t & 7) << 2;
    float4 f = *(const float4*)&src[(size_t)(by * 32 + tr) * C + nb * 32 + tc];
    tile[tr][tc + 0] = f2bf(f.x); tile[tr][tc + 1] = f2bf(f.y);
    tile[tr][tc + 2] = f2bf(f.z); tile[tr][tc + 3] = f2bf(f.w);
    __syncthreads();
    u16x4 o;
    o[0] = tile[tc + 0][tr]; o[1] = tile[tc + 1][tr];
    o[2] = tile[tc + 2][tr]; o[3] = tile[tc + 3][tr];
    *(u16x4*)&dbase[(size_t)(nb * 32 + tr) * 2048 + by * 32 + tc] = o;
}

// ---------------------------------------------------------------------------
// m97-style GEMM: C[M x N] = A[M x 2048] * Bt[N x 2048]^T, bf16 inputs.
// MODE 0: segmented qkv epilogue with FUSED ROPE (q,k roped; v transposed).
// MODE 1: fp32 C, N=2048.
// ---------------------------------------------------------------------------
template <int MODE>
__global__ __launch_bounds__(256) void gemm2(const u16* __restrict__ A,
                                             const u16* __restrict__ Bt,
                                             u16* __restrict__ oq, u16* __restrict__ ok,
                                             u16* __restrict__ ov, float* __restrict__ of) {
    __shared__ u16 As[128 * 32];
    __shared__ u16 Bs[128 * 32];
    const int t = threadIdx.x, w = t >> 6, lane = t & 63;
    const int l15 = lane & 15, quad = lane >> 4;
    const int m0 = blockIdx.y << 7, n0 = blockIdx.x << 7;
    const int K = 2048;
    const int c0 = w * 2, c1 = c0 + 1;
    const int ar0 = c0 * 16 + (lane >> 2), ar1 = c1 * 16 + (lane >> 2);
    const int ac = (lane & 3) << 3;
    const u16* Ap0 = A + (size_t)(m0 + ar0) * K + ac;
    const u16* Ap1 = A + (size_t)(m0 + ar1) * K + ac;
    const u16* Bp0 = Bt + (size_t)(n0 + ar0) * K + ac;
    const u16* Bp1 = Bt + (size_t)(n0 + ar1) * K + ac;
    const int wm = (w >> 1) << 6, wn = (w & 1) << 6;

    f32x4 acc[4][4] = {};

    for (int k0 = 0; k0 < K; k0 += 32) {
        GLDS16(Ap0 + k0, &As[c0 * 512]);
        GLDS16(Ap1 + k0, &As[c1 * 512]);
        GLDS16(Bp0 + k0, &Bs[c0 * 512]);
        GLDS16(Bp1 + k0, &Bs[c1 * 512]);
        __syncthreads();
        bf16x8 a[4], bfr[4];
#pragma unroll
        for (int mt = 0; mt < 4; ++mt)
            a[mt] = *(bf16x8*)&As[(wm + mt * 16 + l15) * 32 + quad * 8];
#pragma unroll
        for (int nt = 0; nt < 4; ++nt)
            bfr[nt] = *(bf16x8*)&Bs[(wn + nt * 16 + l15) * 32 + quad * 8];
#pragma unroll
        for (int mt = 0; mt < 4; ++mt)
#pragma unroll
            for (int nt = 0; nt < 4; ++nt)
                acc[mt][nt] = __builtin_amdgcn_mfma_f32_16x16x32_bf16(a[mt], bfr[nt], acc[mt][nt], 0, 0, 0);
        __syncthreads();
    }

    if constexpr (MODE == 0) {
        // Wave's 64-col span (wn) is exactly one head. RoPE for Q/K heads:
        // d = nt*16+l15 in [0,64); d<32: out = x[d]c - x[2d+1]s ; d>=32: out = x[d]c + x[2(d-32)]s.
        const int colbase = n0 + wn;
        const bool isv = (colbase >= 2560);
        float iv[4];
        if (!isv) {
#pragma unroll
            for (int nt = 0; nt < 4; ++nt)
                iv[nt] = exp2f(-0.4152410118609253f * (float)(nt * 8 + (l15 >> 1)));
        }
        const int map1 = (quad << 4) | ((2 * l15 + 1) & 15);  // odd partners (d<32)
        const int map2 = (quad << 4) | ((2 * l15) & 15);      // even partners (d>=32)
        const bool lo = (l15 < 8);
#pragma unroll
        for (int mt = 0; mt < 4; ++mt)
#pragma unroll
            for (int r = 0; r < 4; ++r) {
                const int row = m0 + wm + mt * 16 + quad * 4 + r;
                float v0 = acc[mt][0][r], v1 = acc[mt][1][r];
                float v2 = acc[mt][2][r], v3 = acc[mt][3][r];
                float o0 = v0, o1 = v1, o2 = v2, o3 = v3;
                if (!isv) {
                    float g1a = __shfl(v0, map1), g1b = __shfl(v1, map1);
                    float g1c = __shfl(v2, map1), g1d = __shfl(v3, map1);
                    float g2a = __shfl(v0, map2), g2b = __shfl(v1, map2);
                    float g2c = __shfl(v2, map2), g2d = __shfl(v3, map2);
                    float p0 = lo ? g1a : g1b;   // x[2d+1] for nt=0
                    float p1 = lo ? g1c : g1d;   // x[2d+1] for nt=1
                    float p2 = lo ? g2a : g2b;   // x[2(d-32)] for nt=2
                    float p3 = lo ? g2c : g2d;   // x[2(d-32)] for nt=3
                    const float tt = (float)(row & 2047);
                    float sn, cs;
                    __sincosf(tt * iv[0], &sn, &cs); o0 = v0 * cs - p0 * sn;
                    __sincosf(tt * iv[1], &sn, &cs); o1 = v1 * cs - p1 * sn;
                    __sincosf(tt * iv[2], &sn, &cs); o2 = v2 * cs + p2 * sn;
                    __sincosf(tt * iv[3], &sn, &cs); o3 = v3 * cs + p3 * sn;
                }
                float o[4] = {o0, o1, o2, o3};
                if (colbase < 2048) {
#pragma unroll
                    for (int nt = 0; nt < 4; ++nt)
                        oq[(size_t)row * 2048 + colbase + nt * 16 + l15] = f2bf(o[nt]);
                } else if (colbase < 2560) {
#pragma unroll
                    for (int nt = 0; nt < 4; ++nt)
                        ok[(size_t)row * 512 + colbase - 2048 + nt * 16 + l15] = f2bf(o[nt]);
                } else {
#pragma unroll
                    for (int nt = 0; nt < 4; ++nt)
                        ov[(size_t)(colbase - 2560 + nt * 16 + l15) * 4096 + row] = f2bf(o[nt]);
                }
            }
    } else {
#pragma unroll
        for (int mt = 0; mt < 4; ++mt)
#pragma unroll
            for (int nt = 0; nt < 4; ++nt)
#pragma unroll
                for (int r = 0; r < 4; ++r) {
                    int row = m0 + wm + mt * 16 + quad * 4 + r;
                    int col = n0 + wn + nt * 16 + l15;
                    of[(size_t)row * 2048 + col] = acc[mt][nt][r];
                }
    }
}

// ---------------------------------------------------------------------------
// Flash attention v4 — S^T formulation + register-prefetch pipeline.
// Block = (bx, kvh, b); waves = 4 Q-heads; groups g=bx and 63-bx (33 tiles).
// ---------------------------------------------------------------------------
__global__ __launch_bounds__(256, 3) void attn4(const u16* __restrict__ q,
                                                const u16* __restrict__ k,
                                                const u16* __restrict__ vT,
                                                u16* __restrict__ att) {
    __shared__ u16 Ks[64 * 72];     // [key][d]
    __shared__ u16 Vt[64 * 72];     // [d][key]
    __shared__ u16 Pw[4][16 * 72];  // per-wave P^T

    const int t = threadIdx.x, w = t >> 6, lane = t & 63;
    const int l15 = lane & 15, quad = lane >> 4;
    const int bx = blockIdx.x, kvh = blockIdx.y, b = blockIdx.z;
    const int h = kvh * 4 + w;
    const size_t rowbase = (size_t)b * 2048;
    const int sr = t >> 2, sd = (t & 3) << 4;
    u16* Pq = &Pw[w][0];
    const float SC = 0.125f * 1.4426950408889634f;  // 1/sqrt(64) * log2(e)

    const u16* kbase = &k[(rowbase + sr) * 512 + kvh * 64 + sd];
    const u16* vbase = &vT[(size_t)(kvh * 64 + sr) * 4096 + rowbase + sd];

    for (int grp = 0; grp < 2; ++grp) {
        const int g = grp ? (63 - bx) : bx;
        const int qbase = g * 32;
        const int ntiles = (g >> 1) + 1;

        bf16x8 aq[2][2];
#pragma unroll
        for (int mt = 0; mt < 2; ++mt)
#pragma unroll
            for (int kc = 0; kc < 2; ++kc)
                aq[mt][kc] = *(const bf16x8*)&q[(rowbase + qbase + mt * 16 + l15) * 2048 +
                                               h * 64 + kc * 32 + quad * 8];

        f32x4 acc[2][4] = {};
        float m_i[2] = {-INFINITY, -INFINITY};
        float l_i[2] = {0.f, 0.f};

        // prefetch tile 0
        u16x8 pk0 = *(const u16x8*)kbase;
        u16x8 pk1 = *(const u16x8*)(kbase + 8);
        u16x8 pv0 = *(const u16x8*)vbase;
        u16x8 pv1 = *(const u16x8*)(vbase + 8);

        for (int kb = 0; kb < ntiles; ++kb) {
            __syncthreads();   // previous tile's LDS reads complete
            *(u16x8*)&Ks[sr * 72 + sd]     = pk0;
            *(u16x8*)&Ks[sr * 72 + sd + 8] = pk1;
            *(u16x8*)&Vt[sr * 72 + sd]     = pv0;
            *(u16x8*)&Vt[sr * 72 + sd + 8] = pv1;
            if (kb + 1 < ntiles) {
                const u16* kp = kbase + (size_t)(kb + 1) * 64 * 512;
                pk0 = *(const u16x8*)kp;
                pk1 = *(const u16x8*)(kp + 8);
                const u16* vp = vbase + (size_t)(kb + 1) * 64;
                pv0 = *(const u16x8*)vp;
                pv1 = *(const u16x8*)(vp + 8);
            }
            __syncthreads();   // tile visible

            // S^T for both mt, sharing K-frag reads
            f32x4 st[2][4] = {};
#pragma unroll
            for (int kt = 0; kt < 4; ++kt) {
                bf16x8 ak0 = *(bf16x8*)&Ks[(kt * 16 + l15) * 72 + quad * 8];
                bf16x8 ak1 = *(bf16x8*)&Ks[(kt * 16 + l15) * 72 + 32 + quad * 8];
                st[0][kt] = __builtin_amdgcn_mfma_f32_16x16x32_bf16(ak0, aq[0][0], st[0][kt], 0, 0, 0);
                st[0][kt] = __builtin_amdgcn_mfma_f32_16x16x32_bf16(ak1, aq[0][1], st[0][kt], 0, 0, 0);
                st[1][kt] = __builtin_amdgcn_mfma_f32_16x16x32_bf16(ak0, aq[1][0], st[1][kt], 0, 0, 0);
                st[1][kt] = __builtin_amdgcn_mfma_f32_16x16x32_bf16(ak1, aq[1][1], st[1][kt], 0, 0, 0);
            }
            const bool diag = (kb == ntiles - 1);

#pragma unroll
            for (int mt = 0; mt < 2; ++mt) {
                float sv[16];
#pragma unroll
                for (int kt = 0; kt < 4; ++kt)
#pragma unroll
                    for (int r = 0; r < 4; ++r) sv[kt * 4 + r] = st[mt][kt][r] * SC;
                if (diag) {
                    const int qg = qbase + mt * 16 + l15;
#pragma unroll
                    for (int kt = 0; kt < 4; ++kt)
#pragma unroll
                        for (int r = 0; r < 4; ++r) {
                            int key = kb * 64 + kt * 16 + quad * 4 + r;
                            if (key > qg) sv[kt * 4 + r] = -INFINITY;
                        }
                }
                float mx = sv[0];
#pragma unroll
                for (int i = 1; i < 16; ++i) mx = fmaxf(mx, sv[i]);
                mx = fmaxf(mx, __shfl_xor(mx, 16));
                mx = fmaxf(mx, __shfl_xor(mx, 32));
                float mnew = fmaxf(m_i[mt], mx);
                float sum = 0.f;
#pragma unroll
                for (int i = 0; i < 16; ++i) {
                    sv[i] = __builtin_amdgcn_exp2f(sv[i] - mnew);
                    sum += sv[i];
                }
                sum += __shfl_xor(sum, 16);
                sum += __shfl_xor(sum, 32);
                float alpha = __builtin_amdgcn_exp2f(m_i[mt] - mnew);
                l_i[mt] = l_i[mt] * alpha + sum;
                m_i[mt] = mnew;

#pragma unroll
                for (int kt = 0; kt < 4; ++kt) {
                    uint2 uu;
                    uu.x = pkbf(sv[kt * 4 + 0], sv[kt * 4 + 1]);
                    uu.y = pkbf(sv[kt * 4 + 2], sv[kt * 4 + 3]);
                    *(uint2*)&Pq[l15 * 72 + kt * 16 + quad * 4] = uu;
                }
                bf16x8 bp0 = *(bf16x8*)&Pq[l15 * 72 + quad * 8];
                bf16x8 bp1 = *(bf16x8*)&Pq[l15 * 72 + 32 + quad * 8];

#pragma unroll
                for (int dt = 0; dt < 4; ++dt) {
                    bf16x8 av0 = *(bf16x8*)&Vt[(dt * 16 + l15) * 72 + quad * 8];
                    bf16x8 av1 = *(bf16x8*)&Vt[(dt * 16 + l15) * 72 + 32 + quad * 8];
#pragma unroll
                    for (int r = 0; r < 4; ++r) acc[mt][dt][r] *= alpha;
                    acc[mt][dt] = __builtin_amdgcn_mfma_f32_16x16x32_bf16(av0, bp0, acc[mt][dt], 0, 0, 0);
                    acc[mt][dt] = __builtin_amdgcn_mfma_f32_16x16x32_bf16(av1, bp1, acc[mt][dt], 0, 0, 0);
                }
            }
        }

        // epilogue: O^T lane(d = dt*16+quad*4+r, q = l15)
#pragma unroll
        for (int mt = 0; mt < 2; ++mt) {
            float inv = 1.0f / l_i[mt];
            size_t row = rowbase + qbase + mt * 16 + l15;
#pragma unroll
            for (int dt = 0; dt < 4; ++dt) {
                uint2 uu;
                uu.x = pkbf(acc[mt][dt][0] * inv, acc[mt][dt][1] * inv);
                uu.y = pkbf(acc[mt][dt][2] * inv, acc[mt][dt][3] * inv);
                *(uint2*)&att[row * 2048 + h * 64 + dt * 16 + quad * 4] = uu;
            }
        }
    }
}

// ---------------------------------------------------------------------------
extern "C" void kernel_launch(void* const* d_in, const int* in_sizes, int n_in,
                              void* d_out, int out_size, void* d_ws, size_t ws_size,
                              hipStream_t stream) {
    const float* x  = (const float*)d_in[0];
    const float* Wq = (const float*)d_in[2];
    const float* Wk = (const float*)d_in[3];
    const float* Wv = (const float*)d_in[4];
    const float* Wo = (const float*)d_in[5];
    float* out = (float*)d_out;

    u16* xb = (u16*)d_out;                                   // bf16 x in d_out (dead before final write)

    u16* q     = (u16*)d_ws;                                 // 4096x2048
    u16* kk    = q + (size_t)4096 * 2048;                    // 4096x512
    u16* vt    = kk + (size_t)4096 * 512;                    // 512x4096 (V^T)
    u16* wqkvt = vt + (size_t)4096 * 512;                    // 3072x2048 (dead after QKV gemm)
    u16* att   = wqkvt;                                      // 4096x2048 aliases dead wqkvt
    u16* wot   = kk;                                         // 2048x2048 aliases dead kk+vt (after attn)

    cvt_x<<<4096, 256, 0, stream>>>(x, xb);
    tcvt3<<<dim3(96, 64), 256, 0, stream>>>(Wq, Wk, Wv, wqkvt);
    gemm2<0><<<dim3(24, 32), 256, 0, stream>>>(xb, wqkvt, q, kk, vt, nullptr);  // rope fused
    attn4<<<dim3(32, 8, 2), 256, 0, stream>>>(q, kk, vt, att);
    tcvt<<<dim3(64, 64), 256, 0, stream>>>(Wo, wot, 2048);
    gemm2<1><<<dim3(16, 32), 256, 0, stream>>>(att, wot, nullptr, nullptr, nullptr, out);
}